// Round 2
// baseline (1525.245 us; speedup 1.0000x reference)
//
#include <hip/hip_runtime.h>
#include <math.h>

// ---------------------------------------------------------------------------
// x: [6144] fp32; 6 layers 6144x6144 + ReLU; 1 layer 4096x6144 + Swish.
// Outputs: [4M] pdist3(x), [4M] pdist2(y), [4096] y.  The "min" offsets
// cancel in pairwise differences and are never computed.
//
// Round-1 finding: per-wave load depth is NOT the limiter (neutral result).
// The 7 separate GEMV dispatches each run at ~1.4 TB/s (~108 us) vs the
// 6.7 TB/s the poison fills prove this allocation sustains.
// This version fuses the whole chain into ONE persistent kernel:
//   * 512 blocks (2/CU guaranteed: __launch_bounds__(256,2), 24KB LDS)
//   * grid-stride rows, 3 rows/wave -> same streaming pattern, no boundaries
//   * device-scope release/acquire grid barrier between layers
//     (threadfence flushes XCD L2; acquire fence invalidates stale L1/L2)
//   * activations ping-pong in d_ws; layer 7 writes y straight to d_out
// ---------------------------------------------------------------------------

#define K_DIM   6144
#define NV      (K_DIM / 4)      // 1536 float4 = 24 KB
#define WITER   24               // float4 loads per row per lane
#define NBLOCKS 512
#define NWAVES  (NBLOCKS * 4)    // 2048 waves

struct Params {
    const float* W[7];
    const float* b[7];
    const float* x;      // layer-1 input
    float*       act0;   // ws ping (6144 f)
    float*       act1;   // ws pong (6144 f)
    float*       y;      // d_out latent (4096 f)
    unsigned int* bar;   // 8 u32 barrier counters (zeroed per launch)
};

__global__ __launch_bounds__(256, 2) void mlp_fused(Params p)
{
    __shared__ float4 xs[NV];                    // 24 KB

    const int wid  = threadIdx.x >> 6;
    const int lane = threadIdx.x & 63;
    const int gw   = blockIdx.x * 4 + wid;       // 0 .. 2047

    const float* in = p.x;

    for (int L = 0; L < 7; ++L) {
        // ---- stage current activation vector into LDS (coalesced float4)
        const float4* __restrict__ ing = (const float4*)in;
        for (int i = threadIdx.x; i < NV; i += 256)
            xs[i] = ing[i];
        __syncthreads();

        const int nRows = (L == 6) ? 4096 : 6144;
        float* outp = (L == 6) ? p.y : ((L & 1) ? p.act1 : p.act0);
        const float* __restrict__ bias = p.b[L];

        for (int r = gw; r < nRows; r += NWAVES) {            // 3 (or 2) rows/wave
            const float4* __restrict__ Wr =
                (const float4*)(p.W[L] + (size_t)r * K_DIM);

            // issue the whole 24 KB row back-to-back (static idx -> VGPRs)
            float4 w[WITER];
#pragma unroll
            for (int i = 0; i < WITER; ++i)
                w[i] = Wr[i * 64 + lane];

            float a0 = 0.f, a1 = 0.f, a2 = 0.f, a3 = 0.f;
#pragma unroll
            for (int i = 0; i < WITER; ++i) {
                float4 v = xs[i * 64 + lane];
                a0 = fmaf(w[i].x, v.x, a0);
                a1 = fmaf(w[i].y, v.y, a1);
                a2 = fmaf(w[i].z, v.z, a2);
                a3 = fmaf(w[i].w, v.w, a3);
            }
            float acc = (a0 + a1) + (a2 + a3);
#pragma unroll
            for (int off = 32; off > 0; off >>= 1)
                acc += __shfl_down(acc, off, 64);

            if (lane == 0) {
                float z = acc + bias[r];
                outp[r] = (L < 6) ? fmaxf(z, 0.f)
                                  : z / (1.f + expf(-z));     // Swish
            }
        }

        if (L < 6) {
            // ---- grid-wide barrier with device-scope release/acquire ----
            __syncthreads();        // each wave's stores drained (vmcnt) at barrier
            __threadfence();        // every thread: flush this XCD's L2 (release)
            __syncthreads();        // all flushes done before leader arrives
            if (threadIdx.x == 0) {
                __hip_atomic_fetch_add(&p.bar[L], 1u,
                                       __ATOMIC_RELEASE, __HIP_MEMORY_SCOPE_AGENT);
                while (__hip_atomic_load(&p.bar[L],
                                         __ATOMIC_ACQUIRE, __HIP_MEMORY_SCOPE_AGENT)
                       < (unsigned)NBLOCKS)
                    __builtin_amdgcn_s_sleep(2);
            }
            __syncthreads();        // block released by leader
            __threadfence();        // every thread: invalidate stale L1/L2 (acquire)
            in = (L & 1) ? p.act1 : p.act0;    // buffer layer L just wrote
        }
    }
}

// Pairwise L2 distance, 3-dim points. 2048x2048 outputs, 16.8 MB coalesced write.
__global__ __launch_bounds__(256) void pdist3_kernel(
    const float* __restrict__ x, float* __restrict__ out)
{
    const int idx = blockIdx.x * 256 + threadIdx.x;
    const int n = idx >> 11;
    const int m = idx & 2047;
    float a0 = x[3 * n + 0], a1 = x[3 * n + 1], a2 = x[3 * n + 2];
    float c0 = x[3 * m + 0], c1 = x[3 * m + 1], c2 = x[3 * m + 2];
    float d0 = a0 - c0, d1 = a1 - c1, d2 = a2 - c2;
    float s = d0 * d0 + d1 * d1 + d2 * d2;
    out[idx] = (s > 0.f) ? sqrtf(s) : 0.f;
}

// Pairwise L2 distance, 2-dim points.
__global__ __launch_bounds__(256) void pdist2_kernel(
    const float* __restrict__ y, float* __restrict__ out)
{
    const int idx = blockIdx.x * 256 + threadIdx.x;
    const int n = idx >> 11;
    const int m = idx & 2047;
    float a0 = y[2 * n + 0], a1 = y[2 * n + 1];
    float c0 = y[2 * m + 0], c1 = y[2 * m + 1];
    float d0 = a0 - c0, d1 = a1 - c1;
    float s = d0 * d0 + d1 * d1;
    out[idx] = (s > 0.f) ? sqrtf(s) : 0.f;
}

extern "C" void kernel_launch(void* const* d_in, const int* in_sizes, int n_in,
                              void* d_out, int out_size, void* d_ws, size_t ws_size,
                              hipStream_t stream)
{
    const float* x = (const float*)d_in[0];

    Params p;
    for (int i = 0; i < 7; ++i) {
        p.W[i] = (const float*)d_in[1 + 2 * i];
        p.b[i] = (const float*)d_in[2 + 2 * i];
    }
    p.x = x;

    float* out      = (float*)d_out;
    float* in_dist  = out;                       // 2048*2048
    float* lat_dist = out + 2048 * 2048;         // 2048*2048
    float* y        = out + 2 * 2048 * 2048;     // 4096 (lat_repr)

    float* ws = (float*)d_ws;
    p.act0 = ws;                                 // 6144 f
    p.act1 = ws + K_DIM;                         // 6144 f
    p.y    = y;
    p.bar  = (unsigned int*)(ws + 2 * K_DIM);    // 8 u32

    // zero the barrier counters (capture-safe memset node)
    hipMemsetAsync(p.bar, 0, 8 * sizeof(unsigned int), stream);

    const int BS  = 256;
    const int gPD = (2048 * 2048) / BS;

    // input-side distances depend only on x — tiny, run first
    pdist3_kernel<<<gPD, BS, 0, stream>>>(x, in_dist);

    // whole GEMV chain: one persistent dispatch (512 blocks = 2/CU resident)
    mlp_fused<<<NBLOCKS, BS, 0, stream>>>(p);

    // latent-side distances read y from d_out
    pdist2_kernel<<<gPD, BS, 0, stream>>>(y, lat_dist);
}